// Round 6
// baseline (297.000 us; speedup 1.0000x reference)
//
#include <hip/hip_runtime.h>
#include <hip/hip_bf16.h>
#include <stdint.h>

// Flash-attention (causal, GQA) B=4, S=1024, HQ=32, HK=8, D=128, fp32 io.
// R4-R9 history: 32x32x16 MFMAs, S^T orientation, kappa-permuted K (P exits
// softmax in PV A-layout), pair-blocks (p,7-p) for causal balance, XCD
// grouping (bx&7=hk), bf16 prep-pass images + global_load_lds DMA dbuf.
// R10: (a) exp2f was the R8/R9 VALU regression (OCML precise path, not
//   v_exp_f32): VALU work +36% R7->R9. Fix: inline-asm v_exp_f32.
//   (b) occupancy 2x via IN-BLOCK SPLIT-K: 512-thr blocks, 8 waves =
//   4 rowsets x 2 K-halves; half kh sweeps 32-key tiles of parity kh
//   (BK=32); exact flash-merge of (m,l,O) partials at phase end through
//   LDS (KV buffers reused as scratch). 512 blocks x 512 thr = 16 waves/CU
//   (4/SIMD, was 8/CU); per-CU work still exactly balanced (18 steps).
//   __launch_bounds__(512,4) caps VGPR at 128; BK=32 keeps one s-chunk
//   live (accO 64 + qf 32 + s 16 + ka 8 fits).
//
// Layout facts (m74/m101-verified): 32x32 C/D: col=lane&31,
// row=(reg&3)+8*(reg>>2)+4*(lane>>5). A: m=lane&31, k=(lane>>5)*8+j.
// B: n=lane&31, k=(lane>>5)*8+j.
// kappa: key kk (0..31) sits at slot mu = (kk&3)+4*((kk>>3)&1)
// +8*(2*((kk>>4)&1)+((kk>>2)&1)) => P regs [8cp..8cp+7] are PV A-frags.

typedef __bf16 v8bf __attribute__((ext_vector_type(8)));
typedef __bf16 v4bf __attribute__((ext_vector_type(4)));
typedef float  v16f __attribute__((ext_vector_type(16)));

#define NB  4
#define NS  1024
#define NHQ 32
#define NHK 8
#define ND  128
#define BQ  128
#define BK  32

#define KOFF(r) (16*((r)>>3) + ((((r)>>2)&1)*4) + ((r)&3))

__device__ __forceinline__ float fexp2(float x) {
  float r; asm("v_exp_f32 %0, %1" : "=v"(r) : "v"(x)); return r;
}

// ---------------- pre-pass: fp32 K/V -> bf16 32-key tile images -----------
// tileid = (b*8+hk)*32 + t (t = 32-key tile), 16 KB per tile at tileid<<14:
//  K image [0,8K): 8 regions dM of 1 KB: byte = dM*1024 + half*512 + mu*16
//    + j*2  (d = dM*16 + half*8 + j, mu = kappa slot of key)
//  V image [8K,16K): byte = (d>>1)*128 + (g^((d>>1)&3))*32 + (d&1)*16,
//    holding keys 8g..8g+7 (granule g = 0..3) for dim d.
__global__ __launch_bounds__(256)
void prep(const float* __restrict__ kg, const float* __restrict__ vg,
          char* __restrict__ ws)
{
  const int tid = threadIdx.x;
  const int blk = blockIdx.x;
  if (blk < 4096) {                 // ---- K: 1M threads, float4 -> 8B write
    int gid = blk * 256 + tid;
    int i  = gid & 31;              // d-quad, d = 4i..4i+3
    int s  = (gid >> 5) & (NS - 1); // key within (b,hk)
    int hk = (gid >> 15) & 7;
    int b  = gid >> 18;
    float4 f = *(const float4*)(kg + ((size_t)((b * NS + s) * NHK + hk)) * ND + 4 * i);
    v4bf kb;
    kb[0]=(__bf16)f.x; kb[1]=(__bf16)f.y; kb[2]=(__bf16)f.z; kb[3]=(__bf16)f.w;
    int t  = s >> 5;
    int kk = s & 31;
    int mu = (kk & 3) + 4 * ((kk >> 3) & 1)
           + 8 * (2 * ((kk >> 4) & 1) + ((kk >> 2) & 1));
    int dM    = i >> 2;
    int halfb = (i >> 1) & 1;
    int byte  = dM * 1024 + halfb * 512 + mu * 16 + ((4 * i) & 7) * 2;
    size_t tb = (size_t)((b * 8 + hk) * 32 + t) << 14;
    *(v4bf*)(ws + tb + byte) = kb;
  } else {                          // ---- V: 0.5M threads, 8 gathers -> 16B
    int vid = (blk - 4096) * 256 + tid;
    int d  = vid & 127;
    int g  = (vid >> 7) & 3;        // granule = 8 keys
    int t  = (vid >> 9) & 31;
    int hk = (vid >> 14) & 7;
    int b  = vid >> 17;
    const float* vp = vg + ((size_t)((b * NS + t * 32 + g * 8) * NHK + hk)) * ND + d;
    v8bf w;
    #pragma unroll
    for (int e = 0; e < 8; ++e) w[e] = (__bf16)vp[(size_t)e * (NHK * ND)];
    int byte = (d >> 1) * 128 + ((g ^ ((d >> 1) & 3)) * 32) + (d & 1) * 16;
    size_t tb = (size_t)((b * 8 + hk) * 32 + t) << 14;
    *(v8bf*)(ws + tb + 8192 + byte) = w;
  }
}

// ---------------- main kernel --------------------------------------------
__global__ __launch_bounds__(512, 4)
void fattn(const float* __restrict__ qg, const char* __restrict__ kvg,
           float* __restrict__ og)
{
  __shared__ __align__(16) char  KV[2][32768];  // [buf][parity 16K each]
  __shared__ __align__(16) float alq[8 * 32];   // per-wave alpha / inv-l
  __shared__ __align__(16) float mex[2 * 4 * 32];  // split-K m exchange
  __shared__ __align__(16) float lex[2 * 4 * 32];  // split-K l' exchange

  const int tid  = threadIdx.x;
  const int lane = tid & 63;
  const int wave = tid >> 6;       // 0..7
  const int half = lane >> 5;
  const int l31  = lane & 31;
  const int rs4  = wave & 3;       // row-set
  const int kh   = wave >> 2;      // K-half (tile parity)

  // XCD-grouped decode: bx = ((b*16 + p*4 + c) << 3) | hk
  const int bx = blockIdx.x;
  const int hk = bx & 7;
  const int t6 = bx >> 3;
  const int b  = t6 >> 4;
  const int m6 = t6 & 15;
  const int p  = m6 >> 2;                // q-tile pair id: tiles (p, 7-p)
  const int h  = hk * 4 + (m6 & 3);

  // 1/sqrt(128) * log2(e): softmax runs in exp2 domain
  const float scale = 0.12751879523604785f;
  const int kvtile = (b * 8 + hk) * 32;  // ws tile-id base (32-key tiles)

  // DMA one step's tile pair (2s, 2s+1) = 32 KB contiguous; 4 chunks/wave.
  auto dma = [&](int s_, char* dst) {
    const char* src = kvg + ((size_t)(kvtile + 2 * s_) << 14);
    #pragma unroll
    for (int i = 0; i < 4; ++i) {
      int c = wave * 4 + i;
      __builtin_amdgcn_global_load_lds(
        (const __attribute__((address_space(1))) void*)(src + c * 1024 + lane * 16),
        (__attribute__((address_space(3))) void*)(dst + c * 1024),
        16, 0, 0);
    }
  };

  for (int ph = 0; ph < 2; ++ph) {
    const int qt = ph ? (7 - p) : p;
    const int rv = ph ? (3 - rs4) : rs4;     // reverse rowsets in phase B
    const int q0 = qt * BQ;
    const int wqb = q0 + rv * 32;
    const int qglob = wqb + l31;
    const int nsteps = 2 * (qt + 1);         // steps of 2x32-key tiles

    // prime DMA chain for this phase (KV was merge scratch at phase end)
    dma(0, KV[0]);
    int cur = 0;

    // Q fragments (B-operand: n=q=l31, k=d=dM*16+half*8+j), scale folded
    v8bf qf[8];
    {
      const float* qp = qg + ((size_t)((b * NS + qglob) * NHQ + h)) * ND + half * 8;
      #pragma unroll
      for (int dM = 0; dM < 8; ++dM) {
        float4 f0 = *(const float4*)(qp + dM * 16);
        float4 f1 = *(const float4*)(qp + dM * 16 + 4);
        v8bf t;
        t[0]=(__bf16)(f0.x*scale); t[1]=(__bf16)(f0.y*scale);
        t[2]=(__bf16)(f0.z*scale); t[3]=(__bf16)(f0.w*scale);
        t[4]=(__bf16)(f1.x*scale); t[5]=(__bf16)(f1.y*scale);
        t[6]=(__bf16)(f1.z*scale); t[7]=(__bf16)(f1.w*scale);
        qf[dM] = t;
      }
    }

    v16f accO[4];
    #pragma unroll
    for (int dt = 0; dt < 4; ++dt)
      #pragma unroll
      for (int e = 0; e < 16; ++e) accO[dt][e] = 0.f;
    float m_run = -INFINITY, l_run = 0.f;

    for (int s = 0; s < nsteps; ++s) {
      // my DMA into KV[cur] landed; all waves done reading KV[cur^1]
      asm volatile("s_waitcnt vmcnt(0)" ::: "memory");
      __syncthreads();
      if (s + 1 < nsteps) dma(s + 1, KV[cur ^ 1]);

      const int k0w = (2 * s + kh) * 32;     // this wave's tile key base
      if (k0w <= wqb + 31) {
        const char* kb = KV[cur] + kh * 16384;
        v16f s0;
        #pragma unroll
        for (int e = 0; e < 16; ++e) s0[e] = 0.f;
        __builtin_amdgcn_s_setprio(1);
        #pragma unroll
        for (int dM = 0; dM < 8; ++dM) {
          v8bf ka = *(const v8bf*)(kb + dM * 1024 + lane * 16);
          s0 = __builtin_amdgcn_mfma_f32_32x32x16_bf16(ka, qf[dM], s0, 0, 0, 0);
        }
        __builtin_amdgcn_s_setprio(0);
        // causal mask (diagonal tiles only)
        if (k0w + BK > wqb) {
          #pragma unroll
          for (int r = 0; r < 16; ++r)
            if (k0w + KOFF(r) + half * 8 > qglob) s0[r] = -INFINITY;
        }
        // online softmax (exp2 domain), tree reductions
        float t8[8];
        #pragma unroll
        for (int i = 0; i < 8; ++i) t8[i] = fmaxf(s0[i], s0[i + 8]);
        #pragma unroll
        for (int i = 0; i < 4; ++i) t8[i] = fmaxf(t8[i], t8[i + 4]);
        float m0 = fmaxf(fmaxf(t8[0], t8[2]), fmaxf(t8[1], t8[3]));
        m0 = fmaxf(m0, __shfl_xor(m0, 32));
        float mn = fmaxf(m_run, m0);
        #pragma unroll
        for (int r = 0; r < 16; ++r) s0[r] = fexp2(s0[r] - mn);
        float u8[8];
        #pragma unroll
        for (int i = 0; i < 8; ++i) u8[i] = s0[i] + s0[i + 8];
        #pragma unroll
        for (int i = 0; i < 4; ++i) u8[i] = u8[i] + u8[i + 4];
        float rs = (u8[0] + u8[2]) + (u8[1] + u8[3]);
        rs += __shfl_xor(rs, 32);
        // defer-rescale: alpha==1 for every lane -> skip (exact)
        if (__any(m0 > m_run)) {
          float al = fexp2(m_run - mn);
          if (half == 0) alq[wave * 32 + l31] = al;
          float4 alf[4];
          #pragma unroll
          for (int c = 0; c < 4; ++c)
            alf[c] = *(const float4*)(&alq[wave * 32 + 8 * c + 4 * half]);
          #pragma unroll
          for (int dt = 0; dt < 4; ++dt)
            #pragma unroll
            for (int r = 0; r < 16; ++r)
              accO[dt][r] *= ((const float*)&alf[r >> 2])[r & 3];
          l_run = l_run * al + rs;
        } else {
          l_run += rs;
        }
        m_run = mn;
        // O += P V (A = P kappa-aligned in regs, B = V image)
        __builtin_amdgcn_s_setprio(1);
        #pragma unroll
        for (int cp = 0; cp < 2; ++cp) {
          v8bf pf;
          #pragma unroll
          for (int e = 0; e < 8; ++e) pf[e] = (__bf16)s0[cp * 8 + e];
          int g = cp * 2 + half;
          #pragma unroll
          for (int dt = 0; dt < 4; ++dt) {
            int dh = dt * 16 + (l31 >> 1);   // d>>1
            v8bf vb = *(const v8bf*)(kb + 8192 + dh * 128
                        + ((g ^ (dh & 3)) * 32) + (l31 & 1) * 16);
            accO[dt] = __builtin_amdgcn_mfma_f32_32x32x16_bf16(pf, vb, accO[dt], 0, 0, 0);
          }
        }
        __builtin_amdgcn_s_setprio(0);
      }
      cur ^= 1;
    }

    // ---- phase-end split-K merge (exact flash merge via LDS) ----
    if (half == 0) mex[(kh * 4 + rs4) * 32 + l31] = m_run;
    __syncthreads();                         // #1: KV reads done, mex ready
    float m_oth = mex[((kh ^ 1) * 4 + rs4) * 32 + l31];
    float M = fmaxf(m_run, m_oth);
    float a = fexp2(m_run - M);              // 0 if m_run == -inf
    float lw = l_run * a;
    if (half == 0) { alq[wave * 32 + l31] = a; lex[(kh * 4 + rs4) * 32 + l31] = lw; }
    {
      float4 af[4];
      #pragma unroll
      for (int c = 0; c < 4; ++c)
        af[c] = *(const float4*)(&alq[wave * 32 + 8 * c + 4 * half]);
      #pragma unroll
      for (int dt = 0; dt < 4; ++dt)
        #pragma unroll
        for (int r = 0; r < 16; ++r)
          accO[dt][r] *= ((const float*)&af[r >> 2])[r & 3];
    }
    float* mscr = (float*)&KV[0][0];         // 64 KB scratch: rs4*4096 floats
    if (kh == 1) {
      #pragma unroll
      for (int dt = 0; dt < 4; ++dt) {
        int col = dt * 32 + l31;
        #pragma unroll
        for (int q = 0; q < 4; ++q) {
          int qi = 2 * q + half;
          float4 w = make_float4(accO[dt][4*q], accO[dt][4*q+1],
                                 accO[dt][4*q+2], accO[dt][4*q+3]);
          *(float4*)(mscr + rs4 * 4096 + col * 32 + ((qi ^ (col & 7)) << 2)) = w;
        }
      }
    }
    __syncthreads();                         // #2: scratch written
    float l_fin = 1.f;
    if (kh == 0) {
      l_fin = lw + lex[(4 + rs4) * 32 + l31];
      #pragma unroll
      for (int dt = 0; dt < 4; ++dt) {
        int col = dt * 32 + l31;
        #pragma unroll
        for (int q = 0; q < 4; ++q) {
          int qi = 2 * q + half;
          float4 r4 = *(const float4*)(mscr + rs4 * 4096 + col * 32 + ((qi ^ (col & 7)) << 2));
          accO[dt][4*q]   += r4.x; accO[dt][4*q+1] += r4.y;
          accO[dt][4*q+2] += r4.z; accO[dt][4*q+3] += r4.w;
        }
      }
    }
    __syncthreads();                         // #3: scratch reads done

    if (kh == 0) {
      // epilogue: O / l, fp32 stores (kh0 waves only)
      if (half == 0) alq[wave * 32 + l31] = 1.f / l_fin;
      float4 invf[4];
      #pragma unroll
      for (int c = 0; c < 4; ++c)
        invf[c] = *(const float4*)(&alq[wave * 32 + 8 * c + 4 * half]);
      #pragma unroll
      for (int dt = 0; dt < 4; ++dt) {
        #pragma unroll
        for (int r = 0; r < 16; ++r) {
          int qrow = (r & 3) + 8 * (r >> 2) + 4 * half;
          float* op = og + ((size_t)((b * NS + wqb + qrow) * NHQ + h)) * ND;
          op[dt * 32 + l31] = accO[dt][r] * ((const float*)&invf[r >> 2])[r & 3];
        }
      }
    }
  }
}

extern "C" void kernel_launch(void* const* d_in, const int* in_sizes, int n_in,
                              void* d_out, int out_size, void* d_ws, size_t ws_size,
                              hipStream_t stream) {
  const float* q = (const float*)d_in[0];
  const float* k = (const float*)d_in[1];
  const float* v = (const float*)d_in[2];
  float* out = (float*)d_out;
  char* ws = (char*)d_ws;   // 16 MiB: 1024 tiles x 16 KB (K frag | V image)
  prep<<<dim3(4096 + 2048), 256, 0, stream>>>(k, v, ws);
  fattn<<<dim3(NB * NHQ * 4), 512, 0, stream>>>(q, ws, out);
}